// Round 1
// baseline (1430.385 us; speedup 1.0000x reference)
//
#include <hip/hip_runtime.h>
#include <math.h>

#define Bn 2048
#define Sn 50
#define Dn 64
#define Ln 500
#define Kn 4
#define Nn 100000
#define TAUc 0.1f

__device__ __forceinline__ float wsum(float v) {
#pragma unroll
  for (int off = 32; off >= 1; off >>= 1) v += __shfl_xor(v, off, 64);
  return v;
}
__device__ __forceinline__ float wmax(float v) {
#pragma unroll
  for (int off = 32; off >= 1; off >>= 1) v = fmaxf(v, __shfl_xor(v, off, 64));
  return v;
}

// One block per batch element b. 256 threads = 4 waves.
// lanes index the D=64 (or L-chunk) dimension; waves split s (or own k, K=4).
__global__ __launch_bounds__(256) void sine_main(
    const int* __restrict__ seq, const float* __restrict__ emb,
    const float* __restrict__ Cm, const float* __restrict__ w1,
    const float* __restrict__ w2, const float* __restrict__ w3,
    const float* __restrict__ w4, const float* __restrict__ wk1,
    const float* __restrict__ wk2,
    const float* __restrict__ ln2w, const float* __restrict__ ln2b,
    const float* __restrict__ ln4w, const float* __restrict__ ln4b,
    float* __restrict__ vu)
{
  __shared__ float xu[Sn][Dn];      // gathered item embeddings
  __shared__ float W[Dn][Dn];       // staged weight: w1 -> w3 -> wk1[k]x4 -> w3
  __shared__ float xubar[Sn][Dn];
  __shared__ float su[Ln];
  __shared__ float w2s[Dn], w4s[Dn];
  __shared__ float xs[Sn], as_[Sn];
  __shared__ float zu[Dn];
  __shared__ float stopv[Kn];
  __shared__ int   stopi[Kn];
  __shared__ float Cu[Kn][Dn], Cun[Kn][Dn];
  __shared__ float Pkt[Sn][Kn];     // P_k_t_b (softmaxed over k)
  __shared__ float mulkv[Kn][Sn];   // raw P_t_k scores, then mul_p
  __shared__ float delta[Kn][Dn];
  __shared__ float cxs[Sn];

  const int t = threadIdx.x, w = t >> 6, lane = t & 63;
  const int b = blockIdx.x;

  // ---- stage x_u (gather), w1->W, w2, w4
  for (int i = t; i < Sn * Dn; i += 256) {
    int s = i >> 6, d = i & 63;
    xu[s][d] = emb[(size_t)seq[b * Sn + s] * Dn + d];
  }
  for (int i = t; i < Dn * Dn; i += 256) W[i >> 6][i & 63] = w1[i];
  if (t < Dn) { w2s[t] = w2[t]; w4s[t] = w4[t]; }
  __syncthreads();

  // ---- x[s] = tanh(x_u @ w1) @ w2
  for (int s = w; s < Sn; s += 4) {
    float acc = 0.f;
#pragma unroll
    for (int d = 0; d < Dn; ++d) acc = fmaf(xu[s][d], W[d][lane], acc);
    float v = tanhf(acc) * w2s[lane];
    v = wsum(v);
    if (lane == 0) xs[s] = v;
  }
  __syncthreads();

  // ---- a = softmax(x) over s  (wave 0)
  if (w == 0) {
    float v = (lane < Sn) ? xs[lane] : -INFINITY;
    float m = wmax(v);
    float e = (lane < Sn) ? expf(v - m) : 0.f;
    float sm = wsum(e);
    if (lane < Sn) as_[lane] = e / sm;
  }
  __syncthreads();

  // ---- z_u[d] = sum_s a[s]*x_u[s,d]  (wave 0, lane=d)
  if (w == 0) {
    float acc = 0.f;
    for (int s = 0; s < Sn; ++s) acc = fmaf(as_[s], xu[s][lane], acc);
    zu[lane] = acc;
  }
  __syncthreads();

  // ---- s_u[l] = z_u . C[l]
  for (int l = t; l < Ln; l += 256) {
    const float4* cr = (const float4*)(Cm + l * Dn);
    float acc = 0.f;
#pragma unroll
    for (int q = 0; q < Dn / 4; ++q) {
      float4 c = cr[q];
      acc = fmaf(c.x, zu[4 * q + 0], acc);
      acc = fmaf(c.y, zu[4 * q + 1], acc);
      acc = fmaf(c.z, zu[4 * q + 2], acc);
      acc = fmaf(c.w, zu[4 * q + 3], acc);
    }
    su[l] = acc;
  }
  __syncthreads();

  // ---- top-K of s_u (wave 0). argsort-ascending-last-K: ties -> larger index wins.
  if (w == 0) {
    float vals[8]; int idxs[8];
#pragma unroll
    for (int j = 0; j < 8; ++j) {
      int l = lane + 64 * j;
      vals[j] = (l < Ln) ? su[l] : -INFINITY;
      idxs[j] = l;
    }
#pragma unroll
    for (int k = 0; k < Kn; ++k) {
      float bv = -INFINITY; int bi = -1;
#pragma unroll
      for (int j = 0; j < 8; ++j)
        if (vals[j] > bv || (vals[j] == bv && idxs[j] > bi)) { bv = vals[j]; bi = idxs[j]; }
#pragma unroll
      for (int off = 32; off >= 1; off >>= 1) {
        float ov = __shfl_xor(bv, off, 64);
        int   oi = __shfl_xor(bi, off, 64);
        if (ov > bv || (ov == bv && oi > bi)) { bv = ov; bi = oi; }
      }
      if (lane == 0) { stopv[Kn - 1 - k] = bv; stopi[Kn - 1 - k] = bi; }
#pragma unroll
      for (int j = 0; j < 8; ++j) if (idxs[j] == bi) vals[j] = -INFINITY;
    }
  }
  __syncthreads();

  // ---- C_u = C[idx]*sigmoid(s_top); C_u_norm = LN(C_u)  (wave k, lane=d)
  {
    const int k = w;
    float sv = stopv[k]; int si = stopi[k];
    float sig = 1.f / (1.f + expf(-sv));
    float cu = Cm[si * Dn + lane] * sig;
    Cu[k][lane] = cu;
    float m = wsum(cu) * (1.f / Dn);
    float dmv = cu - m;
    float var = wsum(dmv * dmv) * (1.f / Dn);
    float cun = dmv * rsqrtf(var + 1e-12f) * ln2w[lane] + ln2b[lane];
    Cun[k][lane] = cun;
  }
  __syncthreads();
  for (int i = t; i < Dn * Dn; i += 256) W[i >> 6][i & 63] = w3[i];
  __syncthreads();

  // ---- w3_x_u_norm, P_k_t, softmax over k -> Pkt[s][k]
  for (int s = w; s < Sn; s += 4) {
    float acc = 0.f;
#pragma unroll
    for (int d = 0; d < Dn; ++d) acc = fmaf(xu[s][d], W[d][lane], acc);
    float n2 = wsum(acc * acc);
    float yn = acc / fmaxf(sqrtf(n2), 1e-12f);
    float p0 = wsum(yn * Cun[0][lane]);
    float p1 = wsum(yn * Cun[1][lane]);
    float p2 = wsum(yn * Cun[2][lane]);
    float p3 = wsum(yn * Cun[3][lane]);
    float m = fmaxf(fmaxf(p0, p1), fmaxf(p2, p3));
    float e0 = expf(p0 - m), e1 = expf(p1 - m), e2 = expf(p2 - m), e3 = expf(p3 - m);
    float inv = 1.f / (e0 + e1 + e2 + e3);
    if (lane < 4) Pkt[s][lane] = ((lane == 0) ? e0 : (lane == 1) ? e1 : (lane == 2) ? e2 : e3) * inv;
  }
  __syncthreads();

  // ---- P_t_k raw scores: for each k, stage wk1[k] then all waves split s
#pragma unroll 1
  for (int k = 0; k < Kn; ++k) {
    for (int i = t; i < Dn * Dn; i += 256) W[i >> 6][i & 63] = wk1[k * Dn * Dn + i];
    __syncthreads();
    float wk2v = wk2[k * Dn + lane];
    for (int s = w; s < Sn; s += 4) {
      float acc = 0.f;
#pragma unroll
      for (int d = 0; d < Dn; ++d) acc = fmaf(xu[s][d], W[d][lane], acc);
      float v = tanhf(acc) * wk2v;
      v = wsum(v);
      if (lane == 0) mulkv[k][s] = v;
    }
    __syncthreads();
  }

  // ---- softmax over s per k; mul_p = Pkt^T * P_t_k  (wave k, lane=s)
  {
    const int k = w;
    float v = (lane < Sn) ? mulkv[k][lane] : -INFINITY;
    float m = wmax(v);
    float e = (lane < Sn) ? expf(v - m) : 0.f;
    float sm = wsum(e);
    if (lane < Sn) mulkv[k][lane] = (e / sm) * Pkt[lane][k];
  }
  __syncthreads();

  // ---- delta_k = l2norm(sum_s mul_p[k,s]*x_u[s,:])  (wave k, lane=d)
  {
    const int k = w;
    float acc = 0.f;
    for (int s = 0; s < Sn; ++s) acc = fmaf(mulkv[k][s], xu[s][lane], acc);
    float n2 = wsum(acc * acc);
    delta[k][lane] = acc / fmaxf(sqrtf(n2), 1e-12f);
  }
  __syncthreads();

  // ---- x_u_bar = Pkt @ C_u ; restage w3
  for (int i = t; i < Sn * Dn; i += 256) {
    int s = i >> 6, d = i & 63;
    xubar[s][d] = Pkt[s][0] * Cu[0][d] + Pkt[s][1] * Cu[1][d] +
                  Pkt[s][2] * Cu[2][d] + Pkt[s][3] * Cu[3][d];
  }
  for (int i = t; i < Dn * Dn; i += 256) W[i >> 6][i & 63] = w3[i];
  __syncthreads();

  // ---- C_apt scores = tanh(x_u_bar@w3)@w4
  for (int s = w; s < Sn; s += 4) {
    float acc = 0.f;
#pragma unroll
    for (int d = 0; d < Dn; ++d) acc = fmaf(xubar[s][d], W[d][lane], acc);
    float v = tanhf(acc) * w4s[lane];
    v = wsum(v);
    if (lane == 0) xs[s] = v;
  }
  __syncthreads();
  if (w == 0) {
    float v = (lane < Sn) ? xs[lane] : -INFINITY;
    float m = wmax(v);
    float e = (lane < Sn) ? expf(v - m) : 0.f;
    float sm = wsum(e);
    if (lane < Sn) cxs[lane] = e / sm;
  }
  __syncthreads();

  // ---- C_apt vector, LN4, e_k, v_u  (wave 0, lane=d)
  if (w == 0) {
    float acc = 0.f;
    for (int s = 0; s < Sn; ++s) acc = fmaf(cxs[s], xubar[s][lane], acc);
    float m = wsum(acc) * (1.f / Dn);
    float dmv = acc - m;
    float var = wsum(dmv * dmv) * (1.f / Dn);
    float cn = dmv * rsqrtf(var + 1e-12f) * ln4w[lane] + ln4b[lane];
    float e0 = wsum(delta[0][lane] * cn) * (1.f / TAUc);
    float e1 = wsum(delta[1][lane] * cn) * (1.f / TAUc);
    float e2 = wsum(delta[2][lane] * cn) * (1.f / TAUc);
    float e3 = wsum(delta[3][lane] * cn) * (1.f / TAUc);
    float mm = fmaxf(fmaxf(e0, e1), fmaxf(e2, e3));
    float x0 = expf(e0 - mm), x1 = expf(e1 - mm), x2 = expf(e2 - mm), x3 = expf(e3 - mm);
    float inv = 1.f / (x0 + x1 + x2 + x3);
    float vv = (x0 * delta[0][lane] + x1 * delta[1][lane] +
                x2 * delta[2][lane] + x3 * delta[3][lane]) * inv;
    vu[b * Dn + lane] = vv;
  }
}

// scores[b,n] = v_u[b] . emb[n].  Thread owns one n (emb row in 64 VGPRs),
// loops over a 256-wide b tile; v_u reads are wave-uniform -> scalar loads.
__global__ __launch_bounds__(256) void sine_scores(
    const float* __restrict__ vu, const float* __restrict__ emb,
    float* __restrict__ out)
{
  const int n = blockIdx.x * 256 + threadIdx.x;
  const int b0 = blockIdx.y * 256;
  const bool ok = n < Nn;
  const float4* er = (const float4*)(emb + (size_t)(ok ? n : 0) * Dn);
  float4 ev[16];
#pragma unroll
  for (int i = 0; i < 16; ++i) ev[i] = er[i];
#pragma unroll 1
  for (int b = b0; b < b0 + 256; ++b) {
    const float* vb = vu + b * Dn;
    float acc = 0.f;
#pragma unroll
    for (int i = 0; i < 16; ++i) {
      acc = fmaf(ev[i].x, vb[4 * i + 0], acc);
      acc = fmaf(ev[i].y, vb[4 * i + 1], acc);
      acc = fmaf(ev[i].z, vb[4 * i + 2], acc);
      acc = fmaf(ev[i].w, vb[4 * i + 3], acc);
    }
    if (ok) out[(size_t)b * Nn + n] = acc;
  }
}

extern "C" void kernel_launch(void* const* d_in, const int* in_sizes, int n_in,
                              void* d_out, int out_size, void* d_ws, size_t ws_size,
                              hipStream_t stream) {
  const int*   seq  = (const int*)d_in[0];
  /* d_in[1] = item_seq_len, unused by the forward */
  const float* emb  = (const float*)d_in[2];
  const float* Cm   = (const float*)d_in[3];
  const float* w1   = (const float*)d_in[4];
  const float* w2   = (const float*)d_in[5];
  const float* w3   = (const float*)d_in[6];
  const float* w4   = (const float*)d_in[7];
  const float* wk1  = (const float*)d_in[8];
  const float* wk2  = (const float*)d_in[9];
  const float* ln2w = (const float*)d_in[10];
  const float* ln2b = (const float*)d_in[11];
  const float* ln4w = (const float*)d_in[12];
  const float* ln4b = (const float*)d_in[13];
  float* out = (float*)d_out;
  float* vu  = (float*)d_ws;   // [B, D] f32 = 512 KB

  hipLaunchKernelGGL(sine_main, dim3(Bn), dim3(256), 0, stream,
                     seq, emb, Cm, w1, w2, w3, w4, wk1, wk2,
                     ln2w, ln2b, ln4w, ln4b, vu);
  dim3 g((Nn + 255) / 256, Bn / 256);
  hipLaunchKernelGGL(sine_scores, g, dim3(256), 0, stream, vu, emb, out);
}